// Round 1
// baseline (1756.763 us; speedup 1.0000x reference)
//
#include <hip/hip_runtime.h>
#include <math.h>

// Problem constants
#define Bc 8
#define Nc 19
#define Tc 1000
#define Dc 512
#define BTc (Bc*Tc)        // 8000
#define Mc (BTc*Nc)        // 152000 rows, divisible by 32 (4750 tiles)

typedef short bf16x8 __attribute__((ext_vector_type(8)));
typedef float f32x4 __attribute__((ext_vector_type(4)));

__device__ __forceinline__ unsigned short f2bf(float x) {
    unsigned int u = __float_as_uint(x);
    return (unsigned short)((u + 0x7FFFu + ((u >> 16) & 1u)) >> 16);  // RNE
}

// ---------------------------------------------------------------------------
// Shuffle W (2,512,512) fp32 -> bf16 in MFMA B-operand layout:
// Wshuf[((layer*16+ks)*32 + ntile)*512 + lane*8 + j] = W[layer][ks*32+(lane>>4)*8+j][ntile*16+(lane&15)]
// so each lane's B-fragment is one contiguous 16B load.
// ---------------------------------------------------------------------------
__global__ __launch_bounds__(256) void prep_w_kernel(const float* __restrict__ W,
                                                     unsigned short* __restrict__ Wshuf) {
    int tid = blockIdx.x * 256 + threadIdx.x;   // 2*16*32*512 = 524288 total
    int j     = tid & 7;
    int lane  = (tid >> 3) & 63;
    int ntile = (tid >> 9) & 31;
    int ks    = (tid >> 14) & 15;
    int layer = (tid >> 18) & 1;
    int k = ks * 32 + ((lane >> 4) << 3) + j;
    int n = ntile * 16 + (lane & 15);
    Wshuf[tid] = f2bf(W[layer * (Dc*Dc) + k * Dc + n]);
}

// ---------------------------------------------------------------------------
// Mix kernel: one block per (b,t). Computes row-normalized softplus adjacency,
// P = 0.95*I + 0.05*adj_norm, then x_mixed = P @ x, written bf16 to Amix.
// xin layout (B,N,T,D): row (bt,n) at ((b*19+n)*1000+t)*512.
// Amix layout: row-major (Mc, 512), row index bt*19 + n.
// ---------------------------------------------------------------------------
__global__ __launch_bounds__(256) void mix_kernel(const float* xin,
                                                  const float* __restrict__ adj,
                                                  const float* __restrict__ edge_w,
                                                  const float* __restrict__ edge_b,
                                                  unsigned short* __restrict__ Amix) {
    __shared__ float P[Nc*Nc];
    __shared__ float rs[Nc];
    __shared__ float xs[Nc*Dc];
    int bt = blockIdx.x;
    int b  = bt / Tc;
    int t  = bt - b * Tc;
    int tid = threadIdx.x;
    float ew = edge_w[0], eb = edge_b[0];

    // softplus(adj*ew + eb); adjacency (B,T,N,N) block is contiguous at bt*361
    for (int idx = tid; idx < Nc*Nc; idx += 256) {
        float z = fmaf(adj[(size_t)bt * (Nc*Nc) + idx], ew, eb);
        P[idx] = fmaxf(z, 0.f) + log1pf(expf(-fabsf(z)));   // stable softplus
    }
    // stage x rows
    for (int idx = tid; idx < Nc*Dc; idx += 256) {
        int j = idx >> 9;
        int d = idx & (Dc-1);
        xs[idx] = xin[(((size_t)b*Nc + j)*Tc + t)*Dc + d];
    }
    __syncthreads();
    if (tid < Nc) {
        float s = 0.f;
        #pragma unroll
        for (int j = 0; j < Nc; ++j) s += P[tid*Nc + j];
        rs[tid] = 0.05f / (s + 1e-6f);
    }
    __syncthreads();
    for (int idx = tid; idx < Nc*Nc; idx += 256) {
        int i = idx / Nc;
        int j = idx - i*Nc;
        float v = P[idx] * rs[i];
        if (i == j) v += 0.95f;
        P[idx] = v;
    }
    __syncthreads();

    // each thread owns columns d0, d0+1
    int d0 = tid * 2;
    float2 xv[Nc];
    #pragma unroll
    for (int j = 0; j < Nc; ++j)
        xv[j] = *(const float2*)&xs[j*Dc + d0];

    size_t obase = (size_t)bt * Nc * Dc + d0;
    #pragma unroll
    for (int i = 0; i < Nc; ++i) {
        float a0 = 0.f, a1 = 0.f;
        #pragma unroll
        for (int j = 0; j < Nc; ++j) {
            float p = P[i*Nc + j];
            a0 = fmaf(p, xv[j].x, a0);
            a1 = fmaf(p, xv[j].y, a1);
        }
        unsigned int pack = (unsigned int)f2bf(a0) | ((unsigned int)f2bf(a1) << 16);
        *(unsigned int*)&Amix[obase + (size_t)i * Dc] = pack;
    }
}

// ---------------------------------------------------------------------------
// Fused GEMM: C(32 x 512) = Amix_tile @ W + bias + residual, then LayerNorm
// (gamma,beta) and exact-erf GELU, stored fp32 to out (B,N,T,D) layout.
// 256 threads = 4 waves; wave w owns output cols [w*128, w*128+128).
// mfma_f32_16x16x32_bf16; A staged in LDS (row pad +8 bf16 -> 2-way = free).
// ---------------------------------------------------------------------------
__global__ __launch_bounds__(256) void gemm_fused_kernel(
        const unsigned short* __restrict__ Amix,
        const unsigned short* __restrict__ Wshuf,   // this layer's shuffled W
        const float* xin,                           // residual source (may alias out)
        const float* __restrict__ bias,
        const float* __restrict__ gamma,
        const float* __restrict__ beta,
        float* out) {
    __shared__ unsigned short Alds[32*520];
    __shared__ float ps1[32][4];
    __shared__ float ps2[32][4];
    __shared__ float mu_s[32];
    __shared__ float rs_s[32];

    int tid = threadIdx.x;
    int w = tid >> 6;
    int lane = tid & 63;
    int quad = lane >> 4;
    int ln = lane & 15;
    int r0 = blockIdx.x * 32;

    // stage A tile (32 rows x 512 bf16 = 32KB, contiguous in Amix)
    {
        const ulonglong2* src = (const ulonglong2*)(Amix + (size_t)r0 * Dc);
        #pragma unroll
        for (int c = 0; c < 8; ++c) {
            int chunk = tid + c * 256;           // 0..2047
            int row = chunk >> 6;
            int col = (chunk & 63) * 8;
            *(ulonglong2*)&Alds[row*520 + col] = src[chunk];
        }
    }
    __syncthreads();

    f32x4 acc[2][8];
    #pragma unroll
    for (int mf = 0; mf < 2; ++mf)
        #pragma unroll
        for (int p = 0; p < 8; ++p)
            acc[mf][p] = (f32x4){0.f, 0.f, 0.f, 0.f};

    const bf16x8* wp = (const bf16x8*)Wshuf;
    #pragma unroll 4
    for (int ks = 0; ks < 16; ++ks) {
        bf16x8 a0 = *(const bf16x8*)&Alds[ ln      *520 + ks*32 + quad*8];
        bf16x8 a1 = *(const bf16x8*)&Alds[(16+ln)  *520 + ks*32 + quad*8];
        #pragma unroll
        for (int p = 0; p < 8; ++p) {
            bf16x8 bfr = wp[(size_t)(ks*32 + w*8 + p)*64 + lane];
            acc[0][p] = __builtin_amdgcn_mfma_f32_16x16x32_bf16(a0, bfr, acc[0][p], 0, 0, 0);
            acc[1][p] = __builtin_amdgcn_mfma_f32_16x16x32_bf16(a1, bfr, acc[1][p], 0, 0, 0);
        }
    }

    // per-(mf,reg) global row offsets: row gr = bt*19 + n -> out at ((b*19+n)*1000+t)*512
    size_t rowoff[2][4];
    #pragma unroll
    for (int mf = 0; mf < 2; ++mf) {
        #pragma unroll
        for (int reg = 0; reg < 4; ++reg) {
            int gr = r0 + mf*16 + quad*4 + reg;
            int bt = gr / Nc;
            int n  = gr - bt*Nc;
            int b  = bt / Tc;
            int t  = bt - b*Tc;
            rowoff[mf][reg] = (((size_t)b*Nc + n)*Tc + t)*Dc;
        }
    }
    float bcol[8], gcol[8], betc[8];
    #pragma unroll
    for (int p = 0; p < 8; ++p) {
        int col = (w*8 + p)*16 + ln;
        bcol[p] = bias[col];
        gcol[p] = gamma[col];
        betc[p] = beta[col];
    }

    // z = C + bias + residual; accumulate per-row partial sums
    float s1[2][4], s2[2][4];
    #pragma unroll
    for (int mf = 0; mf < 2; ++mf)
        #pragma unroll
        for (int reg = 0; reg < 4; ++reg) { s1[mf][reg] = 0.f; s2[mf][reg] = 0.f; }

    #pragma unroll
    for (int mf = 0; mf < 2; ++mf) {
        #pragma unroll
        for (int p = 0; p < 8; ++p) {
            int col = (w*8 + p)*16 + ln;
            #pragma unroll
            for (int reg = 0; reg < 4; ++reg) {
                float z = acc[mf][p][reg] + bcol[p] + xin[rowoff[mf][reg] + col];
                acc[mf][p][reg] = z;
                s1[mf][reg] += z;
                s2[mf][reg] = fmaf(z, z, s2[mf][reg]);
            }
        }
    }

    // reduce across the 16 lanes of each quad (rows are quad-local)
    #pragma unroll
    for (int mf = 0; mf < 2; ++mf) {
        #pragma unroll
        for (int reg = 0; reg < 4; ++reg) {
            float a = s1[mf][reg], c = s2[mf][reg];
            #pragma unroll
            for (int off = 1; off < 16; off <<= 1) {
                a += __shfl_xor(a, off, 64);
                c += __shfl_xor(c, off, 64);
            }
            if (ln == 0) {
                int R = mf*16 + quad*4 + reg;
                ps1[R][w] = a;
                ps2[R][w] = c;
            }
        }
    }
    __syncthreads();
    if (tid < 32) {
        float a = ps1[tid][0] + ps1[tid][1] + ps1[tid][2] + ps1[tid][3];
        float c = ps2[tid][0] + ps2[tid][1] + ps2[tid][2] + ps2[tid][3];
        float mu = a * (1.0f/Dc);
        float var = c * (1.0f/Dc) - mu*mu;
        mu_s[tid] = mu;
        rs_s[tid] = rsqrtf(var + 1e-5f);
    }
    __syncthreads();

    // LN + exact GELU + store
    #pragma unroll
    for (int mf = 0; mf < 2; ++mf) {
        #pragma unroll
        for (int reg = 0; reg < 4; ++reg) {
            int R = mf*16 + quad*4 + reg;
            float mu = mu_s[R];
            float rstd = rs_s[R];
            size_t ro = rowoff[mf][reg];
            #pragma unroll
            for (int p = 0; p < 8; ++p) {
                int col = (w*8 + p)*16 + ln;
                float v = (acc[mf][p][reg] - mu) * rstd * gcol[p] + betc[p];
                float g = 0.5f * v * (1.0f + erff(v * 0.70710678118654752f));
                out[ro + col] = g;
            }
        }
    }
}

// ---------------------------------------------------------------------------
extern "C" void kernel_launch(void* const* d_in, const int* in_sizes, int n_in,
                              void* d_out, int out_size, void* d_ws, size_t ws_size,
                              hipStream_t stream) {
    const float* features  = (const float*)d_in[0];
    const float* adjacency = (const float*)d_in[1];
    const float* edge_w    = (const float*)d_in[2];
    const float* edge_b    = (const float*)d_in[3];
    const float* W         = (const float*)d_in[4];
    const float* bias      = (const float*)d_in[5];
    const float* gamma     = (const float*)d_in[6];
    const float* beta      = (const float*)d_in[7];
    float* out = (float*)d_out;

    // ws layout: [Wshuf: 2*512*512 bf16 = 1 MB][Amix: 152000*512 bf16 = 155.6 MB]
    unsigned short* Wshuf = (unsigned short*)d_ws;
    unsigned short* Amix  = Wshuf + 2*Dc*Dc;

    prep_w_kernel<<<2048, 256, 0, stream>>>(W, Wshuf);

    // layer 0: input = features
    mix_kernel<<<BTc, 256, 0, stream>>>(features, adjacency, edge_w, edge_b, Amix);
    gemm_fused_kernel<<<Mc/32, 256, 0, stream>>>(Amix, Wshuf, features,
                                                 bias, gamma, beta, out);
    // layer 1: input = out (d_out holds x in (B,N,T,D) layout)
    mix_kernel<<<BTc, 256, 0, stream>>>(out, adjacency, edge_w, edge_b, Amix);
    gemm_fused_kernel<<<Mc/32, 256, 0, stream>>>(Amix, Wshuf + Dc*Dc, out,
                                                 bias + Dc, gamma + Dc, beta + Dc, out);
}